// Round 4
// baseline (2855.225 us; speedup 1.0000x reference)
//
#include <hip/hip_runtime.h>

// Problem constants
constexpr int BN   = 8;            // batch
constexpr int CIN  = 16;
constexpr int COUT = 32;
constexpr int S    = 24;           // spatial edge
constexpr int P    = S * S;        // 576 pixels per plane
constexpr int SP   = 26;           // padded edge
constexpr int PPAD = SP * SP;      // 676
constexpr int NPIX = P * P;        // 331776
constexpr float EPS = 1e-5f;

// Raw barrier: lgkmcnt(0) orders LDS ops cross-wave, but does NOT drain vmcnt,
// so register-staged global loads stay in flight across the barrier (unlike
// __syncthreads(), where the compiler emits s_waitcnt vmcnt(0)).
__device__ __forceinline__ void barrier_lgkm() {
    asm volatile("s_waitcnt lgkmcnt(0)" ::: "memory");
    __builtin_amdgcn_s_barrier();
    asm volatile("" ::: "memory");
}

__global__ void zero_stats_kernel(float* __restrict__ stats) {
    stats[threadIdx.x] = 0.f;
}

// Kernel A: conv over (hb,wb) plane + bias, write inter, accumulate GN stats.
// One block per (b, ha, wa), XCD-swizzled. Double-buffered xs -> ONE barrier
// per ci; stage-writes overlap compute. Weights wave-uniform via scalar loads.
// launch_bounds(256,5): VGPR cap 102 (natural ~84), occupancy setpoint 5.
__global__ __launch_bounds__(256, 5)
void conv2_kernel(const float* __restrict__ x, const float* __restrict__ w2,
                  const float* __restrict__ b2, float* __restrict__ inter,
                  float* __restrict__ stats)
{
    __shared__ float xs[2][PPAD];            // double-buffered padded ci plane

    const int tid = threadIdx.x;
    const int bid = blockIdx.x;
    const int b   = bid & 7;                 // XCD swizzle: XCD k <- batch k
    const int haw = bid >> 3;

    for (int i = tid; i < 2 * PPAD; i += 256) (&xs[0][0])[i] = 0.f;

    const int wave = tid >> 6, lane = tid & 63;
    const int co0 = wave * 8;
    const int co0u = __builtin_amdgcn_readfirstlane(co0);   // SGPR -> s_load path

    const float4 bA = *(const float4*)(b2 + co0);
    const float4 bB = *(const float4*)(b2 + co0 + 4);
    float4 accA[9], accB[9];
    int base[9];
#pragma unroll
    for (int j = 0; j < 9; ++j) {
        accA[j] = bA; accB[j] = bB;
        const int p = lane + 64 * j;
        const int hb = p / 24, wb = p - hb * 24;
        base[j] = hb * SP + wb;              // read xs[buf][base + kh*26 + kw]
    }

    // staging: thread t<144 loads one float4 (pixels 4t..4t+3; rows are 24=4*6 wide)
    const bool act = tid < 144;
    int xoff = 0;
    if (act) {
        const int hb = tid / 6, wb0 = 4 * (tid % 6);
        xoff = (hb + 1) * SP + (wb0 + 1);
    }
    const float* xb0 = x + ((size_t)(b * CIN) * P + haw) * P;   // + ci*NPIX
    float4 stg = make_float4(0.f, 0.f, 0.f, 0.f);
    if (act) stg = *(const float4*)(xb0 + 4 * tid);

    barrier_lgkm();                          // zeros visible (avoid zero/write race)
    if (act) {
        *(float4*)(&xs[0][xoff]) = stg;      // ci=0 plane
        stg = *(const float4*)(xb0 + (size_t)1 * NPIX + 4 * tid);   // ci=1
    }
    barrier_lgkm();                          // xs[0] visible

#pragma unroll 1
    for (int ci = 0; ci < CIN; ++ci) {
        const float* xcur = &xs[ci & 1][0];
        // stage ci+1 into the other buffer; issue loads for ci+2
        if (ci + 1 < CIN && act) {
            *(float4*)(&xs[(ci + 1) & 1][xoff]) = stg;
            if (ci + 2 < CIN)
                stg = *(const float4*)(xb0 + (size_t)(ci + 2) * NPIX + 4 * tid);
        }
        // wave-uniform weights, scalar loads: w2[co][ci][kh][kw], co stride 144
        const float* wci = w2 + (size_t)co0u * (CIN * 9) + ci * 9;
#pragma unroll
        for (int tap = 0; tap < 9; ++tap) {
            const int off = (tap / 3) * SP + (tap % 3);
            const float wk0 = wci[0 * 144 + tap];
            const float wk1 = wci[1 * 144 + tap];
            const float wk2 = wci[2 * 144 + tap];
            const float wk3 = wci[3 * 144 + tap];
            const float wk4 = wci[4 * 144 + tap];
            const float wk5 = wci[5 * 144 + tap];
            const float wk6 = wci[6 * 144 + tap];
            const float wk7 = wci[7 * 144 + tap];
#pragma unroll
            for (int j = 0; j < 9; ++j) {
                const float v = xcur[base[j] + off];
                accA[j].x = fmaf(v, wk0, accA[j].x);
                accA[j].y = fmaf(v, wk1, accA[j].y);
                accA[j].z = fmaf(v, wk2, accA[j].z);
                accA[j].w = fmaf(v, wk3, accA[j].w);
                accB[j].x = fmaf(v, wk4, accB[j].x);
                accB[j].y = fmaf(v, wk5, accB[j].y);
                accB[j].z = fmaf(v, wk6, accB[j].z);
                accB[j].w = fmaf(v, wk7, accB[j].w);
            }
        }
        barrier_lgkm();   // xs[(ci+1)&1] visible for next iter; reads of xcur done
    }

    // write inter + per-wave GN partial stats (post-bias values)
    float s = 0.f, ss = 0.f;
    float* dst = inter + (size_t)((b * COUT + co0) * P + haw) * P;
#pragma unroll
    for (int j = 0; j < 9; ++j) {
        const int p = lane + 64 * j;
        const float4 a = accA[j], c = accB[j];
        s  += a.x + a.y + a.z + a.w + c.x + c.y + c.z + c.w;
        ss += a.x*a.x + a.y*a.y + a.z*a.z + a.w*a.w
            + c.x*c.x + c.y*c.y + c.z*c.z + c.w*c.w;
        dst[0 * NPIX + p] = a.x; dst[1 * NPIX + p] = a.y;
        dst[2 * NPIX + p] = a.z; dst[3 * NPIX + p] = a.w;
        dst[4 * NPIX + p] = c.x; dst[5 * NPIX + p] = c.y;
        dst[6 * NPIX + p] = c.z; dst[7 * NPIX + p] = c.w;
    }
#pragma unroll
    for (int off = 32; off > 0; off >>= 1) {
        s  += __shfl_down(s, off);
        ss += __shfl_down(ss, off);
    }
    if (lane == 0) {
        atomicAdd(&stats[(b * 4 + wave) * 2 + 0], s);
        atomicAdd(&stats[(b * 4 + wave) * 2 + 1], ss);
    }
}

// Kernel B: finalize GN -> per (b,c) scale/shift
__global__ void gn_finalize_kernel(const float* __restrict__ stats,
                                   const float* __restrict__ gamma,
                                   const float* __restrict__ beta,
                                   float* __restrict__ scale,
                                   float* __restrict__ shift)
{
    const int t = threadIdx.x;           // 256 = 8b * 32c
    const int b = t >> 5, c = t & 31, g = c >> 3;
    const float sum = stats[(b * 4 + g) * 2 + 0];
    const float ssq = stats[(b * 4 + g) * 2 + 1];
    const float invN = 1.f / (8.f * (float)NPIX);
    const float mean = sum * invN;
    const float var  = ssq * invN - mean * mean;
    const float rstd = rsqrtf(var + EPS);
    const float sc   = gamma[c] * rstd;
    scale[t] = sc;
    shift[t] = beta[c] - mean * sc;
}

// Kernel C: conv over (ha,wa) plane; GN+ReLU applied at stage time.
// 9 input planes register-staged per ci (<=6 float4/thread), 2-phase pipelined
// with raw barriers. Border planes pre-zeroed ONCE (identical every ci) ->
// loop writes valid chunks only. Weights wave-uniform via scalar loads.
// launch_bounds(256,5): VGPR cap 102 (natural ~84), occupancy setpoint 5.
__global__ __launch_bounds__(256, 5)
void conv1_kernel(const float* __restrict__ inter, const float* __restrict__ w1,
                  const float* __restrict__ b1, const float* __restrict__ scale,
                  const float* __restrict__ shift, float* __restrict__ out)
{
    __shared__ float pl[9 * P];              // 9 planes of one ci (20736 B)
    __shared__ float scs[COUT], shs[COUT];

    const int tid = threadIdx.x;
    const int bid = blockIdx.x;
    const int b   = bid & 7;                 // XCD swizzle
    const int haw = bid >> 3;
    const int ha  = haw / 24, wa = haw - ha * 24;

    for (int i = tid; i < 9 * P; i += 256) pl[i] = 0.f;   // border planes stay 0
    if (tid < COUT) {
        scs[tid] = scale[b * 32 + tid];
        shs[tid] = shift[b * 32 + tid];
    }

    const int wave = tid >> 6, lane = tid & 63;
    const int co0 = wave * 8;
    const int co0u = __builtin_amdgcn_readfirstlane(co0);   // SGPR -> s_load path

    // per-thread stage chunks: float4 chunk c = tid + 256k, c < 1296.
    // chunk c -> plane q=c/144 (tap), offset within ci = plane_off*576 + 4*(c%144).
    // off[k] < 0  => border/out-of-range chunk: stays zero, never written
    int off[6];
#pragma unroll
    for (int k = 0; k < 6; ++k) {
        const int c = tid + 256 * k;
        off[k] = -1;
        if (c < 1296) {
            const int q = c / 144, r = c - q * 144;
            const int ha2 = ha + q / 3 - 1, wa2 = wa + (q % 3) - 1;
            if (((unsigned)ha2 < 24u) && ((unsigned)wa2 < 24u))
                off[k] = (ha2 * 24 + wa2) * P + 4 * r;
        }
    }

    const float* ib0 = inter + (size_t)(b * COUT) * NPIX;   // + ci*NPIX + off
    float4 stg[6];
#pragma unroll
    for (int k = 0; k < 6; ++k) {
        stg[k] = make_float4(0.f, 0.f, 0.f, 0.f);
        if (off[k] >= 0) stg[k] = *(const float4*)(ib0 + off[k]);
    }

    const float4 bA = *(const float4*)(b1 + co0);
    const float4 bB = *(const float4*)(b1 + co0 + 4);
    float4 accA[9], accB[9];
#pragma unroll
    for (int j = 0; j < 9; ++j) { accA[j] = bA; accB[j] = bB; }

    barrier_lgkm();                          // pl zeros + scs/shs visible

#pragma unroll 1
    for (int ci = 0; ci < COUT; ++ci) {
        const float sc = scs[ci], sh = shs[ci];
        // stage regs -> pl, fusing GN + ReLU; border chunks skipped (stay 0)
#pragma unroll
        for (int k = 0; k < 6; ++k) {
            if (off[k] >= 0) {
                const float4 v = stg[k];
                float4 w;
                w.x = fmaxf(fmaf(v.x, sc, sh), 0.f);
                w.y = fmaxf(fmaf(v.y, sc, sh), 0.f);
                w.z = fmaxf(fmaf(v.z, sc, sh), 0.f);
                w.w = fmaxf(fmaf(v.w, sc, sh), 0.f);
                *(float4*)(pl + 4 * (tid + 256 * k)) = w;
            }
        }
        // issue next-ci loads; they ride across the raw barriers under compute
        if (ci + 1 < COUT) {
            const float* ib = ib0 + (size_t)(ci + 1) * NPIX;
#pragma unroll
            for (int k = 0; k < 6; ++k)
                if (off[k] >= 0) stg[k] = *(const float4*)(ib + off[k]);
        }
        barrier_lgkm();                      // pl(ci) visible to all waves
        // wave-uniform weights, scalar loads: w1[co][ci][kh][kw], co stride 288
        const float* wci = w1 + (size_t)co0u * (COUT * 9) + ci * 9;
#pragma unroll
        for (int tap = 0; tap < 9; ++tap) {
            const float wk0 = wci[0 * 288 + tap];
            const float wk1 = wci[1 * 288 + tap];
            const float wk2 = wci[2 * 288 + tap];
            const float wk3 = wci[3 * 288 + tap];
            const float wk4 = wci[4 * 288 + tap];
            const float wk5 = wci[5 * 288 + tap];
            const float wk6 = wci[6 * 288 + tap];
            const float wk7 = wci[7 * 288 + tap];
#pragma unroll
            for (int j = 0; j < 9; ++j) {
                const float v = pl[tap * P + lane + 64 * j];
                accA[j].x = fmaf(v, wk0, accA[j].x);
                accA[j].y = fmaf(v, wk1, accA[j].y);
                accA[j].z = fmaf(v, wk2, accA[j].z);
                accA[j].w = fmaf(v, wk3, accA[j].w);
                accB[j].x = fmaf(v, wk4, accB[j].x);
                accB[j].y = fmaf(v, wk5, accB[j].y);
                accB[j].z = fmaf(v, wk6, accB[j].z);
                accB[j].w = fmaf(v, wk7, accB[j].w);
            }
        }
        barrier_lgkm();                      // all reads done before next overwrite
    }

    float* dst = out + (size_t)((b * COUT + co0) * P + haw) * P;
#pragma unroll
    for (int j = 0; j < 9; ++j) {
        const int p = lane + 64 * j;
        dst[0 * NPIX + p] = accA[j].x; dst[1 * NPIX + p] = accA[j].y;
        dst[2 * NPIX + p] = accA[j].z; dst[3 * NPIX + p] = accA[j].w;
        dst[4 * NPIX + p] = accB[j].x; dst[5 * NPIX + p] = accB[j].y;
        dst[6 * NPIX + p] = accB[j].z; dst[7 * NPIX + p] = accB[j].w;
    }
}

extern "C" void kernel_launch(void* const* d_in, const int* in_sizes, int n_in,
                              void* d_out, int out_size, void* d_ws, size_t ws_size,
                              hipStream_t stream) {
    const float* x       = (const float*)d_in[0];
    const float* conv1_w = (const float*)d_in[1];
    const float* conv1_b = (const float*)d_in[2];
    const float* conv2_w = (const float*)d_in[3];
    const float* conv2_b = (const float*)d_in[4];
    const float* gamma   = (const float*)d_in[5];
    const float* beta    = (const float*)d_in[6];
    float* out = (float*)d_out;

    float* wsf   = (float*)d_ws;
    float* stats = wsf;            // 64 floats
    float* scale = wsf + 64;       // 256 floats
    float* shift = wsf + 320;      // 256 floats
    float* inter = wsf + 1024;     // 84,934,656 floats

    zero_stats_kernel<<<1, 64, 0, stream>>>(stats);
    conv2_kernel<<<BN * P, 256, 0, stream>>>(x, conv2_w, conv2_b, inter, stats);
    gn_finalize_kernel<<<1, 256, 0, stream>>>(stats, gamma, beta, scale, shift);
    conv1_kernel<<<BN * P, 256, 0, stream>>>(inter, conv1_w, conv1_b,
                                             scale, shift, out);
}

// Round 5
// 2659.359 us; speedup vs baseline: 1.0737x; 1.0737x over previous
//
#include <hip/hip_runtime.h>

// Problem constants
constexpr int BN   = 8;            // batch
constexpr int CIN  = 16;
constexpr int COUT = 32;
constexpr int S    = 24;           // spatial edge
constexpr int P    = S * S;        // 576 pixels per plane
constexpr int SP   = 26;           // padded edge
constexpr int PPAD = SP * SP;      // 676
constexpr int NPIX = P * P;        // 331776
constexpr float EPS = 1e-5f;

// Raw barrier: lgkmcnt(0) orders LDS ops cross-wave, but does NOT drain vmcnt,
// so register-staged global loads stay in flight across the barrier (unlike
// __syncthreads(), where the compiler emits s_waitcnt vmcnt(0)).
// The lgkmcnt(0) also guarantees this wave's ds_reads have completed -> a
// single barrier per iteration is enough for WAR with double-buffered LDS.
__device__ __forceinline__ void barrier_lgkm() {
    asm volatile("s_waitcnt lgkmcnt(0)" ::: "memory");
    __builtin_amdgcn_s_barrier();
    asm volatile("" ::: "memory");
}

__global__ void zero_stats_kernel(float* __restrict__ stats) {
    stats[threadIdx.x] = 0.f;
}

// Kernel A: conv over (hb,wb) plane + bias, write inter, accumulate GN stats.
// One block per (b, ha, wa), XCD-swizzled. Double-buffered xs -> ONE barrier
// per ci; stage-writes overlap compute. Weights wave-uniform via scalar loads.
// launch_bounds(256,3): VGPR cap ~85 (pool=256/SIMD; acc floor is 72) -> no
// spills, 3 blocks/CU. DO NOT raise N: (,4)->64 and (,5)->48 VGPR both spill
// catastrophically (R2/R4: 5.9/8.6 GB scratch traffic).
__global__ __launch_bounds__(256, 3)
void conv2_kernel(const float* __restrict__ x, const float* __restrict__ w2,
                  const float* __restrict__ b2, float* __restrict__ inter,
                  float* __restrict__ stats)
{
    __shared__ float xs[2][PPAD];            // double-buffered padded ci plane

    const int tid = threadIdx.x;
    const int bid = blockIdx.x;
    const int b   = bid & 7;                 // XCD swizzle: XCD k <- batch k
    const int haw = bid >> 3;

    for (int i = tid; i < 2 * PPAD; i += 256) (&xs[0][0])[i] = 0.f;

    const int wave = tid >> 6, lane = tid & 63;
    const int co0 = wave * 8;
    const int co0u = __builtin_amdgcn_readfirstlane(co0);   // SGPR -> s_load path

    const float4 bA = *(const float4*)(b2 + co0);
    const float4 bB = *(const float4*)(b2 + co0 + 4);
    float4 accA[9], accB[9];
    int base[9];
#pragma unroll
    for (int j = 0; j < 9; ++j) {
        accA[j] = bA; accB[j] = bB;
        const int p = lane + 64 * j;
        const int hb = p / 24, wb = p - hb * 24;
        base[j] = hb * SP + wb;              // read xs[buf][base + kh*26 + kw]
    }

    // staging: thread t<144 loads one float4 (pixels 4t..4t+3; rows are 24=4*6 wide)
    const bool act = tid < 144;
    int xoff = 0;
    if (act) {
        const int hb = tid / 6, wb0 = 4 * (tid % 6);
        xoff = (hb + 1) * SP + (wb0 + 1);
    }
    const float* xb0 = x + ((size_t)(b * CIN) * P + haw) * P;   // + ci*NPIX
    float4 stg = make_float4(0.f, 0.f, 0.f, 0.f);
    if (act) stg = *(const float4*)(xb0 + 4 * tid);

    barrier_lgkm();                          // zeros visible (avoid zero/write race)
    if (act) {
        *(float4*)(&xs[0][xoff]) = stg;      // ci=0 plane
        stg = *(const float4*)(xb0 + (size_t)1 * NPIX + 4 * tid);   // ci=1
    }
    barrier_lgkm();                          // xs[0] visible

#pragma unroll 1
    for (int ci = 0; ci < CIN; ++ci) {
        const float* xcur = &xs[ci & 1][0];
        // stage ci+1 into the other buffer; issue loads for ci+2
        if (ci + 1 < CIN && act) {
            *(float4*)(&xs[(ci + 1) & 1][xoff]) = stg;
            if (ci + 2 < CIN)
                stg = *(const float4*)(xb0 + (size_t)(ci + 2) * NPIX + 4 * tid);
        }
        // wave-uniform weights, scalar loads: w2[co][ci][kh][kw], co stride 144
        const float* wci = w2 + (size_t)co0u * (CIN * 9) + ci * 9;
#pragma unroll
        for (int tap = 0; tap < 9; ++tap) {
            const int off = (tap / 3) * SP + (tap % 3);
            const float wk0 = wci[0 * 144 + tap];
            const float wk1 = wci[1 * 144 + tap];
            const float wk2 = wci[2 * 144 + tap];
            const float wk3 = wci[3 * 144 + tap];
            const float wk4 = wci[4 * 144 + tap];
            const float wk5 = wci[5 * 144 + tap];
            const float wk6 = wci[6 * 144 + tap];
            const float wk7 = wci[7 * 144 + tap];
#pragma unroll
            for (int j = 0; j < 9; ++j) {
                const float v = xcur[base[j] + off];
                accA[j].x = fmaf(v, wk0, accA[j].x);
                accA[j].y = fmaf(v, wk1, accA[j].y);
                accA[j].z = fmaf(v, wk2, accA[j].z);
                accA[j].w = fmaf(v, wk3, accA[j].w);
                accB[j].x = fmaf(v, wk4, accB[j].x);
                accB[j].y = fmaf(v, wk5, accB[j].y);
                accB[j].z = fmaf(v, wk6, accB[j].z);
                accB[j].w = fmaf(v, wk7, accB[j].w);
            }
        }
        barrier_lgkm();   // xs[(ci+1)&1] visible for next iter; reads of xcur done
    }

    // write inter + per-wave GN partial stats (post-bias values)
    float s = 0.f, ss = 0.f;
    float* dst = inter + (size_t)((b * COUT + co0) * P + haw) * P;
#pragma unroll
    for (int j = 0; j < 9; ++j) {
        const int p = lane + 64 * j;
        const float4 a = accA[j], c = accB[j];
        s  += a.x + a.y + a.z + a.w + c.x + c.y + c.z + c.w;
        ss += a.x*a.x + a.y*a.y + a.z*a.z + a.w*a.w
            + c.x*c.x + c.y*c.y + c.z*c.z + c.w*c.w;
        dst[0 * NPIX + p] = a.x; dst[1 * NPIX + p] = a.y;
        dst[2 * NPIX + p] = a.z; dst[3 * NPIX + p] = a.w;
        dst[4 * NPIX + p] = c.x; dst[5 * NPIX + p] = c.y;
        dst[6 * NPIX + p] = c.z; dst[7 * NPIX + p] = c.w;
    }
#pragma unroll
    for (int off = 32; off > 0; off >>= 1) {
        s  += __shfl_down(s, off);
        ss += __shfl_down(ss, off);
    }
    if (lane == 0) {
        atomicAdd(&stats[(b * 4 + wave) * 2 + 0], s);
        atomicAdd(&stats[(b * 4 + wave) * 2 + 1], ss);
    }
}

// Kernel B: finalize GN -> per (b,c) scale/shift
__global__ void gn_finalize_kernel(const float* __restrict__ stats,
                                   const float* __restrict__ gamma,
                                   const float* __restrict__ beta,
                                   float* __restrict__ scale,
                                   float* __restrict__ shift)
{
    const int t = threadIdx.x;           // 256 = 8b * 32c
    const int b = t >> 5, c = t & 31, g = c >> 3;
    const float sum = stats[(b * 4 + g) * 2 + 0];
    const float ssq = stats[(b * 4 + g) * 2 + 1];
    const float invN = 1.f / (8.f * (float)NPIX);
    const float mean = sum * invN;
    const float var  = ssq * invN - mean * mean;
    const float rstd = rsqrtf(var + EPS);
    const float sc   = gamma[c] * rstd;
    scale[t] = sc;
    shift[t] = beta[c] - mean * sc;
}

// Kernel C: conv over (ha,wa) plane; GN+ReLU applied at stage time.
// Double-buffered pl (2 x 20.7KB) -> ONE barrier per ci. Border planes zeroed
// once in BOTH buffers (identical every ci); stage loop writes valid chunks
// only. Weights wave-uniform via scalar loads. launch_bounds(256,3).
__global__ __launch_bounds__(256, 3)
void conv1_kernel(const float* __restrict__ inter, const float* __restrict__ w1,
                  const float* __restrict__ b1, const float* __restrict__ scale,
                  const float* __restrict__ shift, float* __restrict__ out)
{
    __shared__ float pl[2][9 * P];           // 2 x 20736 B
    __shared__ float scs[COUT], shs[COUT];

    const int tid = threadIdx.x;
    const int bid = blockIdx.x;
    const int b   = bid & 7;                 // XCD swizzle
    const int haw = bid >> 3;
    const int ha  = haw / 24, wa = haw - ha * 24;

    for (int i = tid; i < 2 * 9 * P; i += 256) (&pl[0][0])[i] = 0.f;
    if (tid < COUT) {
        scs[tid] = scale[b * 32 + tid];
        shs[tid] = shift[b * 32 + tid];
    }

    const int wave = tid >> 6, lane = tid & 63;
    const int co0 = wave * 8;
    const int co0u = __builtin_amdgcn_readfirstlane(co0);   // SGPR -> s_load path

    // per-thread stage chunks: float4 chunk c = tid + 256k, c < 1296.
    // chunk c -> plane q=c/144 (tap), offset within ci = plane_off*576 + 4*(c%144).
    // off[k] < 0  => border/out-of-range chunk: stays zero, never written
    int off[6];
#pragma unroll
    for (int k = 0; k < 6; ++k) {
        const int c = tid + 256 * k;
        off[k] = -1;
        if (c < 1296) {
            const int q = c / 144, r = c - q * 144;
            const int ha2 = ha + q / 3 - 1, wa2 = wa + (q % 3) - 1;
            if (((unsigned)ha2 < 24u) && ((unsigned)wa2 < 24u))
                off[k] = (ha2 * 24 + wa2) * P + 4 * r;
        }
    }

    const float* ib0 = inter + (size_t)(b * COUT) * NPIX;   // + ci*NPIX + off
    float4 stg[6];
#pragma unroll
    for (int k = 0; k < 6; ++k) {
        stg[k] = make_float4(0.f, 0.f, 0.f, 0.f);
        if (off[k] >= 0) stg[k] = *(const float4*)(ib0 + off[k]);
    }

    const float4 bA = *(const float4*)(b1 + co0);
    const float4 bB = *(const float4*)(b1 + co0 + 4);
    float4 accA[9], accB[9];
#pragma unroll
    for (int j = 0; j < 9; ++j) { accA[j] = bA; accB[j] = bB; }

    barrier_lgkm();                          // pl zeros + scs/shs visible

    // prologue: write ci=0 into pl[0] (GN+ReLU fused), issue ci=1 loads
    {
        const float sc = scs[0], sh = shs[0];
#pragma unroll
        for (int k = 0; k < 6; ++k) {
            if (off[k] >= 0) {
                const float4 v = stg[k];
                float4 w;
                w.x = fmaxf(fmaf(v.x, sc, sh), 0.f);
                w.y = fmaxf(fmaf(v.y, sc, sh), 0.f);
                w.z = fmaxf(fmaf(v.z, sc, sh), 0.f);
                w.w = fmaxf(fmaf(v.w, sc, sh), 0.f);
                *(float4*)(&pl[0][0] + 4 * (tid + 256 * k)) = w;
            }
        }
#pragma unroll
        for (int k = 0; k < 6; ++k)
            if (off[k] >= 0) stg[k] = *(const float4*)(ib0 + (size_t)NPIX + off[k]);
    }
    barrier_lgkm();                          // pl[0] visible

#pragma unroll 1
    for (int ci = 0; ci < COUT; ++ci) {
        const float* cur = &pl[ci & 1][0];
        // stage ci+1 into other buffer (GN+ReLU fused); issue loads for ci+2.
        // WAR safe: pl[(ci+1)&1] was last read in iter ci-1, barrier-separated.
        if (ci + 1 < COUT) {
            const float sc = scs[ci + 1], sh = shs[ci + 1];
            float* nxt = &pl[(ci + 1) & 1][0];
#pragma unroll
            for (int k = 0; k < 6; ++k) {
                if (off[k] >= 0) {
                    const float4 v = stg[k];
                    float4 w;
                    w.x = fmaxf(fmaf(v.x, sc, sh), 0.f);
                    w.y = fmaxf(fmaf(v.y, sc, sh), 0.f);
                    w.z = fmaxf(fmaf(v.z, sc, sh), 0.f);
                    w.w = fmaxf(fmaf(v.w, sc, sh), 0.f);
                    *(float4*)(nxt + 4 * (tid + 256 * k)) = w;
                }
            }
            if (ci + 2 < COUT) {
                const float* ib = ib0 + (size_t)(ci + 2) * NPIX;
#pragma unroll
                for (int k = 0; k < 6; ++k)
                    if (off[k] >= 0) stg[k] = *(const float4*)(ib + off[k]);
            }
        }
        // wave-uniform weights, scalar loads: w1[co][ci][kh][kw], co stride 288
        const float* wci = w1 + (size_t)co0u * (COUT * 9) + ci * 9;
#pragma unroll
        for (int tap = 0; tap < 9; ++tap) {
            const float wk0 = wci[0 * 288 + tap];
            const float wk1 = wci[1 * 288 + tap];
            const float wk2 = wci[2 * 288 + tap];
            const float wk3 = wci[3 * 288 + tap];
            const float wk4 = wci[4 * 288 + tap];
            const float wk5 = wci[5 * 288 + tap];
            const float wk6 = wci[6 * 288 + tap];
            const float wk7 = wci[7 * 288 + tap];
#pragma unroll
            for (int j = 0; j < 9; ++j) {
                const float v = cur[tap * P + lane + 64 * j];
                accA[j].x = fmaf(v, wk0, accA[j].x);
                accA[j].y = fmaf(v, wk1, accA[j].y);
                accA[j].z = fmaf(v, wk2, accA[j].z);
                accA[j].w = fmaf(v, wk3, accA[j].w);
                accB[j].x = fmaf(v, wk4, accB[j].x);
                accB[j].y = fmaf(v, wk5, accB[j].y);
                accB[j].z = fmaf(v, wk6, accB[j].z);
                accB[j].w = fmaf(v, wk7, accB[j].w);
            }
        }
        barrier_lgkm();     // pl[(ci+1)&1] visible; reads of cur proven complete
    }

    float* dst = out + (size_t)((b * COUT + co0) * P + haw) * P;
#pragma unroll
    for (int j = 0; j < 9; ++j) {
        const int p = lane + 64 * j;
        dst[0 * NPIX + p] = accA[j].x; dst[1 * NPIX + p] = accA[j].y;
        dst[2 * NPIX + p] = accA[j].z; dst[3 * NPIX + p] = accA[j].w;
        dst[4 * NPIX + p] = accB[j].x; dst[5 * NPIX + p] = accB[j].y;
        dst[6 * NPIX + p] = accB[j].z; dst[7 * NPIX + p] = accB[j].w;
    }
}

extern "C" void kernel_launch(void* const* d_in, const int* in_sizes, int n_in,
                              void* d_out, int out_size, void* d_ws, size_t ws_size,
                              hipStream_t stream) {
    const float* x       = (const float*)d_in[0];
    const float* conv1_w = (const float*)d_in[1];
    const float* conv1_b = (const float*)d_in[2];
    const float* conv2_w = (const float*)d_in[3];
    const float* conv2_b = (const float*)d_in[4];
    const float* gamma   = (const float*)d_in[5];
    const float* beta    = (const float*)d_in[6];
    float* out = (float*)d_out;

    float* wsf   = (float*)d_ws;
    float* stats = wsf;            // 64 floats
    float* scale = wsf + 64;       // 256 floats
    float* shift = wsf + 320;      // 256 floats
    float* inter = wsf + 1024;     // 84,934,656 floats

    zero_stats_kernel<<<1, 64, 0, stream>>>(stats);
    conv2_kernel<<<BN * P, 256, 0, stream>>>(x, conv2_w, conv2_b, inter, stats);
    gn_finalize_kernel<<<1, 256, 0, stream>>>(stats, gamma, beta, scale, shift);
    conv1_kernel<<<BN * P, 256, 0, stream>>>(inter, conv1_w, conv1_b,
                                             scale, shift, out);
}

// Round 6
// 1270.952 us; speedup vs baseline: 2.2465x; 2.0924x over previous
//
#include <hip/hip_runtime.h>

// Problem constants
constexpr int BN   = 8;            // batch
constexpr int CIN  = 16;
constexpr int COUT = 32;
constexpr int S    = 24;           // spatial edge
constexpr int P    = S * S;        // 576 pixels per plane
constexpr int SP   = 26;           // padded edge
constexpr int PPAD = SP * SP;      // 676
constexpr int NPIX = P * P;        // 331776
constexpr int NREP = 8;            // GN stats replicas (atomic contention spread)
constexpr float EPS = 1e-5f;

// Raw barrier: lgkmcnt(0) orders LDS ops cross-wave, but does NOT drain vmcnt,
// so register-staged global loads stay in flight across the barrier (unlike
// __syncthreads(), where the compiler emits s_waitcnt vmcnt(0)).
__device__ __forceinline__ void barrier_lgkm() {
    asm volatile("s_waitcnt lgkmcnt(0)" ::: "memory");
    __builtin_amdgcn_s_barrier();
    asm volatile("" ::: "memory");
}

__global__ void zero_stats_kernel(float* __restrict__ stats) {
    stats[threadIdx.x] = 0.f;
    stats[threadIdx.x + 256] = 0.f;
}

// Kernel A: conv over (hb,wb) plane + bias, write inter, accumulate GN stats.
// One block per (b, ha, wa), XCD-swizzled. 2-phase pipeline: stage ci+1 into
// registers while computing ci; raw barriers keep loads in flight.
// Weights wave-uniform via scalar loads. launch_bounds(256,3): VGPR cap ~85
// (per-SIMD pool = 256 regs; acc floor is 72/thread) -> no spills, 3 blocks/CU.
// DO NOT raise N ((,4)/(,5) spill: R2/R4) and DO NOT restructure the barrier
// scheme (R5's single-barrier dbuf respilled at the same VGPR count).
__global__ __launch_bounds__(256, 3)
void conv2_kernel(const float* __restrict__ x, const float* __restrict__ w2,
                  const float* __restrict__ b2, float* __restrict__ inter,
                  float* __restrict__ stats)
{
    __shared__ float xs[PPAD];               // one padded ci plane (borders stay 0)

    const int tid = threadIdx.x;
    const int bid = blockIdx.x;
    const int b   = bid & 7;                 // XCD swizzle: XCD k <- batch k
    const int haw = bid >> 3;

    for (int i = tid; i < PPAD; i += 256) xs[i] = 0.f;

    const int wave = tid >> 6, lane = tid & 63;
    const int co0 = wave * 8;
    const int co0u = __builtin_amdgcn_readfirstlane(co0);   // SGPR -> s_load path

    const float4 bA = *(const float4*)(b2 + co0);
    const float4 bB = *(const float4*)(b2 + co0 + 4);
    float4 accA[9], accB[9];
    int base[9];
#pragma unroll
    for (int j = 0; j < 9; ++j) {
        accA[j] = bA; accB[j] = bB;
        const int p = lane + 64 * j;
        const int hb = p / 24, wb = p - hb * 24;
        base[j] = hb * SP + wb;              // read xs[base + kh*26 + kw]
    }

    // staging: thread t<144 loads one float4 (pixels 4t..4t+3; rows are 24=4*6 wide)
    const bool act = tid < 144;
    int xoff = 0;
    if (act) {
        const int hb = tid / 6, wb0 = 4 * (tid % 6);
        xoff = (hb + 1) * SP + (wb0 + 1);
    }
    const float* xb0 = x + ((size_t)(b * CIN) * P + haw) * P;   // + ci*NPIX
    float4 stg = make_float4(0.f, 0.f, 0.f, 0.f);
    if (act) stg = *(const float4*)(xb0 + 4 * tid);

    barrier_lgkm();                          // xs zeros visible

#pragma unroll 1
    for (int ci = 0; ci < CIN; ++ci) {
        if (act) *(float4*)(xs + xoff) = stg;           // waits vmcnt for stg only
        if (ci + 1 < CIN && act)                        // issue next-ci loads now;
            stg = *(const float4*)(xb0 + (size_t)(ci + 1) * NPIX + 4 * tid);
        barrier_lgkm();                      // xs(ci) visible; loads stay in flight
        // wave-uniform weights, scalar loads: w2[co][ci][kh][kw], co stride 144
        const float* wci = w2 + (size_t)co0u * (CIN * 9) + ci * 9;
#pragma unroll
        for (int tap = 0; tap < 9; ++tap) {
            const int off = (tap / 3) * SP + (tap % 3);
            const float wk0 = wci[0 * 144 + tap];
            const float wk1 = wci[1 * 144 + tap];
            const float wk2 = wci[2 * 144 + tap];
            const float wk3 = wci[3 * 144 + tap];
            const float wk4 = wci[4 * 144 + tap];
            const float wk5 = wci[5 * 144 + tap];
            const float wk6 = wci[6 * 144 + tap];
            const float wk7 = wci[7 * 144 + tap];
#pragma unroll
            for (int j = 0; j < 9; ++j) {
                const float v = xs[base[j] + off];
                accA[j].x = fmaf(v, wk0, accA[j].x);
                accA[j].y = fmaf(v, wk1, accA[j].y);
                accA[j].z = fmaf(v, wk2, accA[j].z);
                accA[j].w = fmaf(v, wk3, accA[j].w);
                accB[j].x = fmaf(v, wk4, accB[j].x);
                accB[j].y = fmaf(v, wk5, accB[j].y);
                accB[j].z = fmaf(v, wk6, accB[j].z);
                accB[j].w = fmaf(v, wk7, accB[j].w);
            }
        }
        barrier_lgkm();                      // all reads done before next overwrite
    }

    // write inter + per-wave GN partial stats (post-bias values)
    float s = 0.f, ss = 0.f;
    float* dst = inter + (size_t)((b * COUT + co0) * P + haw) * P;
#pragma unroll
    for (int j = 0; j < 9; ++j) {
        const int p = lane + 64 * j;
        const float4 a = accA[j], c = accB[j];
        s  += a.x + a.y + a.z + a.w + c.x + c.y + c.z + c.w;
        ss += a.x*a.x + a.y*a.y + a.z*a.z + a.w*a.w
            + c.x*c.x + c.y*c.y + c.z*c.z + c.w*c.w;
        dst[0 * NPIX + p] = a.x; dst[1 * NPIX + p] = a.y;
        dst[2 * NPIX + p] = a.z; dst[3 * NPIX + p] = a.w;
        dst[4 * NPIX + p] = c.x; dst[5 * NPIX + p] = c.y;
        dst[6 * NPIX + p] = c.z; dst[7 * NPIX + p] = c.w;
    }
#pragma unroll
    for (int off = 32; off > 0; off >>= 1) {
        s  += __shfl_down(s, off);
        ss += __shfl_down(ss, off);
    }
    // spread atomics over NREP replica blocks (256 B apart) to break the
    // single-cache-line serialization (~36.9k atomics on one line otherwise)
    if (lane == 0) {
        float* st = stats + ((unsigned)haw & (NREP - 1)) * 64;
        atomicAdd(&st[(b * 4 + wave) * 2 + 0], s);
        atomicAdd(&st[(b * 4 + wave) * 2 + 1], ss);
    }
}

// Kernel B: finalize GN -> per (b,c) scale/shift (reduces NREP replicas)
__global__ void gn_finalize_kernel(const float* __restrict__ stats,
                                   const float* __restrict__ gamma,
                                   const float* __restrict__ beta,
                                   float* __restrict__ scale,
                                   float* __restrict__ shift)
{
    const int t = threadIdx.x;           // 256 = 8b * 32c
    const int b = t >> 5, c = t & 31, g = c >> 3;
    float sum = 0.f, ssq = 0.f;
#pragma unroll
    for (int r = 0; r < NREP; ++r) {
        sum += stats[r * 64 + (b * 4 + g) * 2 + 0];
        ssq += stats[r * 64 + (b * 4 + g) * 2 + 1];
    }
    const float invN = 1.f / (8.f * (float)NPIX);
    const float mean = sum * invN;
    const float var  = ssq * invN - mean * mean;
    const float rstd = rsqrtf(var + EPS);
    const float sc   = gamma[c] * rstd;
    scale[t] = sc;
    shift[t] = beta[c] - mean * sc;
}

// Kernel C: conv over (ha,wa) plane; GN+ReLU applied at stage time.
// 9 input planes register-staged per ci (<=6 float4/thread), 2-phase pipelined
// with raw barriers. Border planes pre-zeroed ONCE (identical every ci) ->
// loop writes valid chunks only. Weights wave-uniform via scalar loads.
// launch_bounds(256,3): no spills, 3 blocks/CU. BYTE-IDENTICAL to the R3
// version (693 us, VALUBusy 73%) -- its register allocation is fragile; the
// R5 dbuf restructure spilled 6.9 GB at the same VGPR count. Do not touch.
__global__ __launch_bounds__(256, 3)
void conv1_kernel(const float* __restrict__ inter, const float* __restrict__ w1,
                  const float* __restrict__ b1, const float* __restrict__ scale,
                  const float* __restrict__ shift, float* __restrict__ out)
{
    __shared__ float pl[9 * P];              // 9 planes of one ci (20736 B)
    __shared__ float scs[COUT], shs[COUT];

    const int tid = threadIdx.x;
    const int bid = blockIdx.x;
    const int b   = bid & 7;                 // XCD swizzle
    const int haw = bid >> 3;
    const int ha  = haw / 24, wa = haw - ha * 24;

    for (int i = tid; i < 9 * P; i += 256) pl[i] = 0.f;   // border planes stay 0
    if (tid < COUT) {
        scs[tid] = scale[b * 32 + tid];
        shs[tid] = shift[b * 32 + tid];
    }

    const int wave = tid >> 6, lane = tid & 63;
    const int co0 = wave * 8;
    const int co0u = __builtin_amdgcn_readfirstlane(co0);   // SGPR -> s_load path

    // per-thread stage chunks: float4 chunk c = tid + 256k, c < 1296.
    // chunk c -> plane q=c/144 (tap), offset within ci = plane_off*576 + 4*(c%144).
    // off[k] < 0  => border/out-of-range chunk: stays zero, never written
    int off[6];
#pragma unroll
    for (int k = 0; k < 6; ++k) {
        const int c = tid + 256 * k;
        off[k] = -1;
        if (c < 1296) {
            const int q = c / 144, r = c - q * 144;
            const int ha2 = ha + q / 3 - 1, wa2 = wa + (q % 3) - 1;
            if (((unsigned)ha2 < 24u) && ((unsigned)wa2 < 24u))
                off[k] = (ha2 * 24 + wa2) * P + 4 * r;
        }
    }

    const float* ib0 = inter + (size_t)(b * COUT) * NPIX;   // + ci*NPIX + off
    float4 stg[6];
#pragma unroll
    for (int k = 0; k < 6; ++k) {
        stg[k] = make_float4(0.f, 0.f, 0.f, 0.f);
        if (off[k] >= 0) stg[k] = *(const float4*)(ib0 + off[k]);
    }

    const float4 bA = *(const float4*)(b1 + co0);
    const float4 bB = *(const float4*)(b1 + co0 + 4);
    float4 accA[9], accB[9];
#pragma unroll
    for (int j = 0; j < 9; ++j) { accA[j] = bA; accB[j] = bB; }

    barrier_lgkm();                          // pl zeros + scs/shs visible

#pragma unroll 1
    for (int ci = 0; ci < COUT; ++ci) {
        const float sc = scs[ci], sh = shs[ci];
        // stage regs -> pl, fusing GN + ReLU; border chunks skipped (stay 0)
#pragma unroll
        for (int k = 0; k < 6; ++k) {
            if (off[k] >= 0) {
                const float4 v = stg[k];
                float4 w;
                w.x = fmaxf(fmaf(v.x, sc, sh), 0.f);
                w.y = fmaxf(fmaf(v.y, sc, sh), 0.f);
                w.z = fmaxf(fmaf(v.z, sc, sh), 0.f);
                w.w = fmaxf(fmaf(v.w, sc, sh), 0.f);
                *(float4*)(pl + 4 * (tid + 256 * k)) = w;
            }
        }
        // issue next-ci loads; they ride across the raw barriers under compute
        if (ci + 1 < COUT) {
            const float* ib = ib0 + (size_t)(ci + 1) * NPIX;
#pragma unroll
            for (int k = 0; k < 6; ++k)
                if (off[k] >= 0) stg[k] = *(const float4*)(ib + off[k]);
        }
        barrier_lgkm();                      // pl(ci) visible to all waves
        // wave-uniform weights, scalar loads: w1[co][ci][kh][kw], co stride 288
        const float* wci = w1 + (size_t)co0u * (COUT * 9) + ci * 9;
#pragma unroll
        for (int tap = 0; tap < 9; ++tap) {
            const float wk0 = wci[0 * 288 + tap];
            const float wk1 = wci[1 * 288 + tap];
            const float wk2 = wci[2 * 288 + tap];
            const float wk3 = wci[3 * 288 + tap];
            const float wk4 = wci[4 * 288 + tap];
            const float wk5 = wci[5 * 288 + tap];
            const float wk6 = wci[6 * 288 + tap];
            const float wk7 = wci[7 * 288 + tap];
#pragma unroll
            for (int j = 0; j < 9; ++j) {
                const float v = pl[tap * P + lane + 64 * j];
                accA[j].x = fmaf(v, wk0, accA[j].x);
                accA[j].y = fmaf(v, wk1, accA[j].y);
                accA[j].z = fmaf(v, wk2, accA[j].z);
                accA[j].w = fmaf(v, wk3, accA[j].w);
                accB[j].x = fmaf(v, wk4, accB[j].x);
                accB[j].y = fmaf(v, wk5, accB[j].y);
                accB[j].z = fmaf(v, wk6, accB[j].z);
                accB[j].w = fmaf(v, wk7, accB[j].w);
            }
        }
        barrier_lgkm();                      // all reads done before next overwrite
    }

    float* dst = out + (size_t)((b * COUT + co0) * P + haw) * P;
#pragma unroll
    for (int j = 0; j < 9; ++j) {
        const int p = lane + 64 * j;
        dst[0 * NPIX + p] = accA[j].x; dst[1 * NPIX + p] = accA[j].y;
        dst[2 * NPIX + p] = accA[j].z; dst[3 * NPIX + p] = accA[j].w;
        dst[4 * NPIX + p] = accB[j].x; dst[5 * NPIX + p] = accB[j].y;
        dst[6 * NPIX + p] = accB[j].z; dst[7 * NPIX + p] = accB[j].w;
    }
}

extern "C" void kernel_launch(void* const* d_in, const int* in_sizes, int n_in,
                              void* d_out, int out_size, void* d_ws, size_t ws_size,
                              hipStream_t stream) {
    const float* x       = (const float*)d_in[0];
    const float* conv1_w = (const float*)d_in[1];
    const float* conv1_b = (const float*)d_in[2];
    const float* conv2_w = (const float*)d_in[3];
    const float* conv2_b = (const float*)d_in[4];
    const float* gamma   = (const float*)d_in[5];
    const float* beta    = (const float*)d_in[6];
    float* out = (float*)d_out;

    float* wsf   = (float*)d_ws;
    float* stats = wsf;            // NREP*64 = 512 floats
    float* scale = wsf + 512;      // 256 floats
    float* shift = wsf + 768;      // 256 floats
    float* inter = wsf + 1024;     // 84,934,656 floats (unchanged)

    zero_stats_kernel<<<1, 256, 0, stream>>>(stats);
    conv2_kernel<<<BN * P, 256, 0, stream>>>(x, conv2_w, conv2_b, inter, stats);
    gn_finalize_kernel<<<1, 256, 0, stream>>>(stats, gamma, beta, scale, shift);
    conv1_kernel<<<BN * P, 256, 0, stream>>>(inter, conv1_w, conv1_b,
                                             scale, shift, out);
}

// Round 7
// 1265.217 us; speedup vs baseline: 2.2567x; 1.0045x over previous
//
#include <hip/hip_runtime.h>

// Problem constants
constexpr int BN   = 8;            // batch
constexpr int CIN  = 16;
constexpr int COUT = 32;
constexpr int S    = 24;           // spatial edge
constexpr int P    = S * S;        // 576 pixels per plane
constexpr int SP   = 26;           // padded edge
constexpr int PPAD = SP * SP;      // 676
constexpr int NPIX = P * P;        // 331776
constexpr int NREP = 8;            // GN stats replicas (atomic contention spread)
constexpr float EPS = 1e-5f;

// Raw barrier: lgkmcnt(0) orders LDS ops cross-wave, but does NOT drain vmcnt,
// so register-staged global loads stay in flight across the barrier (unlike
// __syncthreads(), where the compiler emits s_waitcnt vmcnt(0)).
__device__ __forceinline__ void barrier_lgkm() {
    asm volatile("s_waitcnt lgkmcnt(0)" ::: "memory");
    __builtin_amdgcn_s_barrier();
    asm volatile("" ::: "memory");
}

__global__ void zero_stats_kernel(float* __restrict__ stats) {
    stats[threadIdx.x] = 0.f;
    stats[threadIdx.x + 256] = 0.f;
}

// Kernel A: conv over (hb,wb) plane + bias, write inter, accumulate GN stats.
// One block per (b, ha, wa), XCD-swizzled.
// NEW (R7): the entire 16-plane input tile (43.3 KB) is staged into LDS ONCE
// -> ZERO barriers inside the 16-ci compute loop (was 2/ci = 32 drains).
// Inner loop is kh-outer / kw-in-registers: the 3 kw reads per (kh,j) are
// adjacent dwords at immediate offsets -> ds_read2_b32 merge, 81 -> ~54 LDS
// instrs per ci (LDS pipe is per-CU-shared; this was why conv2 never scaled
// with occupancy R1->R6). FMA order per acc unchanged (ci,kh,kw) -> bit-equal.
// launch_bounds(256,3): 3 blocks/CU (LDS 43.3KB x3 = 130 <= 160 KB). DO NOT
// raise N ((,4)/(,5) spilled: R2/R4 scratch blowups).
__global__ __launch_bounds__(256, 3)
void conv2_kernel(const float* __restrict__ x, const float* __restrict__ w2,
                  const float* __restrict__ b2, float* __restrict__ inter,
                  float* __restrict__ stats)
{
    __shared__ float xs[CIN][PPAD];          // all 16 padded ci planes, 43,264 B

    const int tid = threadIdx.x;
    const int bid = blockIdx.x;
    const int b   = bid & 7;                 // XCD swizzle: XCD k <- batch k
    const int haw = bid >> 3;

    const int wave = tid >> 6, lane = tid & 63;
    const int co0 = wave * 8;
    const int co0u = __builtin_amdgcn_readfirstlane(co0);   // SGPR -> s_load path

    // issue ALL stage loads first (16 planes = 2304 float4 chunks, 9/thread)
    // chunk c = tid + 256k: ci = c/144, r = c%144 -> pixels 4r..4r+3
    const float* xb0 = x + ((size_t)(b * CIN) * P + haw) * P;   // + ci*NPIX
    float4 stg[9];
    int wo[9];
#pragma unroll
    for (int k = 0; k < 9; ++k) {
        const int c  = tid + 256 * k;
        const int ci = c / 144, r = c - ci * 144;
        stg[k] = *(const float4*)(xb0 + (size_t)ci * NPIX + 4 * r);
        const int hb = r / 6, wb0 = 4 * (r % 6);
        wo[k] = ci * PPAD + (hb + 1) * SP + (wb0 + 1);
    }

    // zero everything (borders must be 0); loads above are in flight meanwhile
    for (int i = tid; i < CIN * PPAD; i += 256) (&xs[0][0])[i] = 0.f;
    barrier_lgkm();                          // zeros visible before interior writes
#pragma unroll
    for (int k = 0; k < 9; ++k)              // each waits vmcnt for its load
        *(float4*)(&xs[0][0] + wo[k]) = stg[k];
    barrier_lgkm();                          // full tile visible

    const float4 bA = *(const float4*)(b2 + co0);
    const float4 bB = *(const float4*)(b2 + co0 + 4);
    float4 accA[9], accB[9];
    int base[9];
#pragma unroll
    for (int j = 0; j < 9; ++j) {
        accA[j] = bA; accB[j] = bB;
        const int p = lane + 64 * j;
        const int hb = p / 24, wb = p - hb * 24;
        base[j] = hb * SP + wb;              // read xs[ci][base + kh*26 + kw]
    }

    // barrier-free compute over all 16 ci
#pragma unroll 1
    for (int ci = 0; ci < CIN; ++ci) {
        const float* xci = &xs[ci][0];
        // wave-uniform weights, scalar loads: w2[co][ci][kh][kw], co stride 144
        const float* wci = w2 + (size_t)co0u * (CIN * 9) + ci * 9;
#pragma unroll
        for (int kh = 0; kh < 3; ++kh) {
            const float* wr = wci + kh * 3;  // + m*144 + kw
            float wk[8][3];
#pragma unroll
            for (int m = 0; m < 8; ++m) {
                wk[m][0] = wr[m * 144 + 0];
                wk[m][1] = wr[m * 144 + 1];
                wk[m][2] = wr[m * 144 + 2];
            }
#pragma unroll
            for (int j = 0; j < 9; ++j) {
                const float* xr = xci + base[j] + kh * SP;
                const float v0 = xr[0];      // adjacent dwords ->
                const float v1 = xr[1];      // ds_read2_b32 + ds_read_b32
                const float v2 = xr[2];
                accA[j].x = fmaf(v0, wk[0][0], fmaf(v1, wk[0][1], fmaf(v2, wk[0][2], accA[j].x)));
                accA[j].y = fmaf(v0, wk[1][0], fmaf(v1, wk[1][1], fmaf(v2, wk[1][2], accA[j].y)));
                accA[j].z = fmaf(v0, wk[2][0], fmaf(v1, wk[2][1], fmaf(v2, wk[2][2], accA[j].z)));
                accA[j].w = fmaf(v0, wk[3][0], fmaf(v1, wk[3][1], fmaf(v2, wk[3][2], accA[j].w)));
                accB[j].x = fmaf(v0, wk[4][0], fmaf(v1, wk[4][1], fmaf(v2, wk[4][2], accB[j].x)));
                accB[j].y = fmaf(v0, wk[5][0], fmaf(v1, wk[5][1], fmaf(v2, wk[5][2], accB[j].y)));
                accB[j].z = fmaf(v0, wk[6][0], fmaf(v1, wk[6][1], fmaf(v2, wk[6][2], accB[j].z)));
                accB[j].w = fmaf(v0, wk[7][0], fmaf(v1, wk[7][1], fmaf(v2, wk[7][2], accB[j].w)));
            }
        }
    }

    // write inter + per-wave GN partial stats (post-bias values)
    float s = 0.f, ss = 0.f;
    float* dst = inter + (size_t)((b * COUT + co0) * P + haw) * P;
#pragma unroll
    for (int j = 0; j < 9; ++j) {
        const int p = lane + 64 * j;
        const float4 a = accA[j], c = accB[j];
        s  += a.x + a.y + a.z + a.w + c.x + c.y + c.z + c.w;
        ss += a.x*a.x + a.y*a.y + a.z*a.z + a.w*a.w
            + c.x*c.x + c.y*c.y + c.z*c.z + c.w*c.w;
        dst[0 * NPIX + p] = a.x; dst[1 * NPIX + p] = a.y;
        dst[2 * NPIX + p] = a.z; dst[3 * NPIX + p] = a.w;
        dst[4 * NPIX + p] = c.x; dst[5 * NPIX + p] = c.y;
        dst[6 * NPIX + p] = c.z; dst[7 * NPIX + p] = c.w;
    }
#pragma unroll
    for (int off = 32; off > 0; off >>= 1) {
        s  += __shfl_down(s, off);
        ss += __shfl_down(ss, off);
    }
    // spread atomics over NREP replica blocks (256 B apart)
    if (lane == 0) {
        float* st = stats + ((unsigned)haw & (NREP - 1)) * 64;
        atomicAdd(&st[(b * 4 + wave) * 2 + 0], s);
        atomicAdd(&st[(b * 4 + wave) * 2 + 1], ss);
    }
}

// Kernel B: finalize GN -> per (b,c) scale/shift (reduces NREP replicas)
__global__ void gn_finalize_kernel(const float* __restrict__ stats,
                                   const float* __restrict__ gamma,
                                   const float* __restrict__ beta,
                                   float* __restrict__ scale,
                                   float* __restrict__ shift)
{
    const int t = threadIdx.x;           // 256 = 8b * 32c
    const int b = t >> 5, c = t & 31, g = c >> 3;
    float sum = 0.f, ssq = 0.f;
#pragma unroll
    for (int r = 0; r < NREP; ++r) {
        sum += stats[r * 64 + (b * 4 + g) * 2 + 0];
        ssq += stats[r * 64 + (b * 4 + g) * 2 + 1];
    }
    const float invN = 1.f / (8.f * (float)NPIX);
    const float mean = sum * invN;
    const float var  = ssq * invN - mean * mean;
    const float rstd = rsqrtf(var + EPS);
    const float sc   = gamma[c] * rstd;
    scale[t] = sc;
    shift[t] = beta[c] - mean * sc;
}

// Kernel C: conv over (ha,wa) plane; GN+ReLU applied at stage time.
// 9 input planes register-staged per ci (<=6 float4/thread), 2-phase pipelined
// with raw barriers. Border planes pre-zeroed ONCE (identical every ci) ->
// loop writes valid chunks only. Weights wave-uniform via scalar loads.
// launch_bounds(256,3): no spills, 3 blocks/CU. BYTE-IDENTICAL to the R3
// version (693 us, VALUBusy 73%) -- its register allocation is fragile; the
// R5 dbuf restructure spilled 6.9 GB at the same VGPR count. Do not touch.
__global__ __launch_bounds__(256, 3)
void conv1_kernel(const float* __restrict__ inter, const float* __restrict__ w1,
                  const float* __restrict__ b1, const float* __restrict__ scale,
                  const float* __restrict__ shift, float* __restrict__ out)
{
    __shared__ float pl[9 * P];              // 9 planes of one ci (20736 B)
    __shared__ float scs[COUT], shs[COUT];

    const int tid = threadIdx.x;
    const int bid = blockIdx.x;
    const int b   = bid & 7;                 // XCD swizzle
    const int haw = bid >> 3;
    const int ha  = haw / 24, wa = haw - ha * 24;

    for (int i = tid; i < 9 * P; i += 256) pl[i] = 0.f;   // border planes stay 0
    if (tid < COUT) {
        scs[tid] = scale[b * 32 + tid];
        shs[tid] = shift[b * 32 + tid];
    }

    const int wave = tid >> 6, lane = tid & 63;
    const int co0 = wave * 8;
    const int co0u = __builtin_amdgcn_readfirstlane(co0);   // SGPR -> s_load path

    // per-thread stage chunks: float4 chunk c = tid + 256k, c < 1296.
    // chunk c -> plane q=c/144 (tap), offset within ci = plane_off*576 + 4*(c%144).
    // off[k] < 0  => border/out-of-range chunk: stays zero, never written
    int off[6];
#pragma unroll
    for (int k = 0; k < 6; ++k) {
        const int c = tid + 256 * k;
        off[k] = -1;
        if (c < 1296) {
            const int q = c / 144, r = c - q * 144;
            const int ha2 = ha + q / 3 - 1, wa2 = wa + (q % 3) - 1;
            if (((unsigned)ha2 < 24u) && ((unsigned)wa2 < 24u))
                off[k] = (ha2 * 24 + wa2) * P + 4 * r;
        }
    }

    const float* ib0 = inter + (size_t)(b * COUT) * NPIX;   // + ci*NPIX + off
    float4 stg[6];
#pragma unroll
    for (int k = 0; k < 6; ++k) {
        stg[k] = make_float4(0.f, 0.f, 0.f, 0.f);
        if (off[k] >= 0) stg[k] = *(const float4*)(ib0 + off[k]);
    }

    const float4 bA = *(const float4*)(b1 + co0);
    const float4 bB = *(const float4*)(b1 + co0 + 4);
    float4 accA[9], accB[9];
#pragma unroll
    for (int j = 0; j < 9; ++j) { accA[j] = bA; accB[j] = bB; }

    barrier_lgkm();                          // pl zeros + scs/shs visible

#pragma unroll 1
    for (int ci = 0; ci < COUT; ++ci) {
        const float sc = scs[ci], sh = shs[ci];
        // stage regs -> pl, fusing GN + ReLU; border chunks skipped (stay 0)
#pragma unroll
        for (int k = 0; k < 6; ++k) {
            if (off[k] >= 0) {
                const float4 v = stg[k];
                float4 w;
                w.x = fmaxf(fmaf(v.x, sc, sh), 0.f);
                w.y = fmaxf(fmaf(v.y, sc, sh), 0.f);
                w.z = fmaxf(fmaf(v.z, sc, sh), 0.f);
                w.w = fmaxf(fmaf(v.w, sc, sh), 0.f);
                *(float4*)(pl + 4 * (tid + 256 * k)) = w;
            }
        }
        // issue next-ci loads; they ride across the raw barriers under compute
        if (ci + 1 < COUT) {
            const float* ib = ib0 + (size_t)(ci + 1) * NPIX;
#pragma unroll
            for (int k = 0; k < 6; ++k)
                if (off[k] >= 0) stg[k] = *(const float4*)(ib + off[k]);
        }
        barrier_lgkm();                      // pl(ci) visible to all waves
        // wave-uniform weights, scalar loads: w1[co][ci][kh][kw], co stride 288
        const float* wci = w1 + (size_t)co0u * (COUT * 9) + ci * 9;
#pragma unroll
        for (int tap = 0; tap < 9; ++tap) {
            const float wk0 = wci[0 * 288 + tap];
            const float wk1 = wci[1 * 288 + tap];
            const float wk2 = wci[2 * 288 + tap];
            const float wk3 = wci[3 * 288 + tap];
            const float wk4 = wci[4 * 288 + tap];
            const float wk5 = wci[5 * 288 + tap];
            const float wk6 = wci[6 * 288 + tap];
            const float wk7 = wci[7 * 288 + tap];
#pragma unroll
            for (int j = 0; j < 9; ++j) {
                const float v = pl[tap * P + lane + 64 * j];
                accA[j].x = fmaf(v, wk0, accA[j].x);
                accA[j].y = fmaf(v, wk1, accA[j].y);
                accA[j].z = fmaf(v, wk2, accA[j].z);
                accA[j].w = fmaf(v, wk3, accA[j].w);
                accB[j].x = fmaf(v, wk4, accB[j].x);
                accB[j].y = fmaf(v, wk5, accB[j].y);
                accB[j].z = fmaf(v, wk6, accB[j].z);
                accB[j].w = fmaf(v, wk7, accB[j].w);
            }
        }
        barrier_lgkm();                      // all reads done before next overwrite
    }

    float* dst = out + (size_t)((b * COUT + co0) * P + haw) * P;
#pragma unroll
    for (int j = 0; j < 9; ++j) {
        const int p = lane + 64 * j;
        dst[0 * NPIX + p] = accA[j].x; dst[1 * NPIX + p] = accA[j].y;
        dst[2 * NPIX + p] = accA[j].z; dst[3 * NPIX + p] = accA[j].w;
        dst[4 * NPIX + p] = accB[j].x; dst[5 * NPIX + p] = accB[j].y;
        dst[6 * NPIX + p] = accB[j].z; dst[7 * NPIX + p] = accB[j].w;
    }
}

extern "C" void kernel_launch(void* const* d_in, const int* in_sizes, int n_in,
                              void* d_out, int out_size, void* d_ws, size_t ws_size,
                              hipStream_t stream) {
    const float* x       = (const float*)d_in[0];
    const float* conv1_w = (const float*)d_in[1];
    const float* conv1_b = (const float*)d_in[2];
    const float* conv2_w = (const float*)d_in[3];
    const float* conv2_b = (const float*)d_in[4];
    const float* gamma   = (const float*)d_in[5];
    const float* beta    = (const float*)d_in[6];
    float* out = (float*)d_out;

    float* wsf   = (float*)d_ws;
    float* stats = wsf;            // NREP*64 = 512 floats
    float* scale = wsf + 512;      // 256 floats
    float* shift = wsf + 768;      // 256 floats
    float* inter = wsf + 1024;     // 84,934,656 floats (unchanged)

    zero_stats_kernel<<<1, 256, 0, stream>>>(stats);
    conv2_kernel<<<BN * P, 256, 0, stream>>>(x, conv2_w, conv2_b, inter, stats);
    gn_finalize_kernel<<<1, 256, 0, stream>>>(stats, gamma, beta, scale, shift);
    conv1_kernel<<<BN * P, 256, 0, stream>>>(inter, conv1_w, conv1_b,
                                             scale, shift, out);
}